// Round 18
// baseline (75.202 us; speedup 1.0000x reference)
//
#include <hip/hip_runtime.h>
#include <hip/hip_bf16.h>

#define BATCH 32
#define CIN   64
#define COUT  128
#define HIN   128
#define WIN   128
#define HOUT  64
#define WOUT  64

typedef unsigned int u32;
typedef unsigned short u16;
typedef __attribute__((ext_vector_type(8))) short short8;
typedef __attribute__((ext_vector_type(4))) float f32x4;

// ---------------- ws layout ----------------
// wsW  : byte       0 ..  262144 : bf16 weights, SWIZZLED image, 8 chunks * 32768 B
//        chunk=i>>3, kk=(i&7)>>1(plane), parity=i&1:
//        byte = o*256 + ((4*kk+kh)^(o&15))*16 + (2*kw+parity)*2
// part : byte  262144 ..  524288 : [128][256] float2 partial sums
// ab   : byte  786432 ..  787456 : [128] float2 (fallback path only)
// wsO  : byte 1048576 .. 34603008: bf16 conv intermediate (fast path only)

__device__ inline u16 f2bf(float v) {
  __hip_bfloat16 h = __float2bfloat16(v);
  return *reinterpret_cast<u16*>(&h);
}
__device__ inline u32 pack2(float a, float b) {
  return (u32)f2bf(a) | ((u32)f2bf(b) << 16);
}

// ---------------- Kernel 1: Gabor filters -> swizzled bf16 image (K=128 chunks) ----------------
__global__ __launch_bounds__(256) void gabor_kernel(
    const float* __restrict__ freq, const float* __restrict__ theta,
    const float* __restrict__ psi,  const float* __restrict__ sigma,
    __hip_bfloat16* __restrict__ wsw) {
  int idx = blockIdx.x * 256 + threadIdx.x;     // 8192 = 128*64
  int o = idx >> 6, i = idx & 63;
  float f = freq[idx], t = theta[idx], p = psi[idx], s = sigma[idx];
  float ct = cosf(t), st = sinf(t);
  float se = s + 0.001f;
  float gsc = -0.5f / (se * se);
  float nrm = 1.0f / (2.0f * 3.14f * s * s);    // PI = 3.14 in the reference
  const float lin[4] = {-1.f, 0.f, 1.f, 2.f};
  int chunk = i >> 3;                 // 8 chunks of 8 input channels
  int kk = (i & 7) >> 1;              // channel-pair plane 0..3
  int parity = i & 1;
  #pragma unroll
  for (int ky = 0; ky < 4; ++ky) {
    #pragma unroll
    for (int kx = 0; kx < 4; ++kx) {
      float xx = lin[kx], yy = lin[ky];
      float rx =  xx * ct + yy * st;
      float ry = -xx * st + yy * ct;
      float g = __expf(gsc * (rx * rx + ry * ry)) * cosf(f * rx + p) * nrm;
      int slot = (4 * kk + ky) ^ (o & 15);
      wsw[(chunk * 32768 + o * 256 + slot * 16 + (2 * kx + parity) * 2) >> 1] =
          __float2bfloat16(g);
    }
  }
}

// ---------------- Kernel 2: implicit-GEMM conv via MFMA ----------------
// Block: 1024 thr (16 waves, 2M x 8N). Tile M=128 x N=512 (8 oh x 64 ow).
// K loop: 8 chunks of 128 (8 input channels) -> HALF the barrier drains of R14.
// A (32 KB/chunk, 256B rows, 16-subtile XOR-o&15 swizzle) via global_load_lds;
// X channel-pair interleaved u32 [4 planes][18 rows][136 ci], reg-staged.
constexpr int XRLEN  = 136;   // u32 per row (ci = iw+3, 0..135)
constexpr int XROWS  = 18;    // ih rows (8 oh -> 18 with halo)
constexpr int XPLANE = 2448;  // u32 per plane (18*136)
constexpr int XBYTES = 39168; // 4 planes * 2448 u32 * 4 B
constexpr int NSLOT  = 2304;  // 4 planes * 18 rows * 32 quads
// LDS: A0 @0, A1 @32768, X0 @65536, X1 @104704 ; total 143872

__global__ __launch_bounds__(1024, 4) void conv_mfma(
    const float* __restrict__ x, const char* __restrict__ wsW,
    float* __restrict__ out, u16* __restrict__ outb,
    float2* __restrict__ part) {
  __shared__ __align__(16) char lds[143872];

  const int tid = threadIdx.x;
  const int l = tid & 63, w = tid >> 6;       // 16 waves
  const int wm = w & 1, wn = w >> 1;          // wm: M-half, wn: N-eighth (0..7)
  const int t4 = l >> 4, lcol = l & 15;
  const int ohb = blockIdx.x, b = blockIdx.y;
  const int oh0 = ohb * 8;

  // ---- X staging precompute: 3 slots/thread, sg = tid + u*1024 (covers 2304) ----
  bool act[3]; int xdw[3]; const float* gpA[3];
  #pragma unroll
  for (int u = 0; u < 3; ++u) {
    int sg = tid + u * 1024;
    int p = sg / 576, rem = sg - p * 576;      // plane = channel pair (0..3)
    int r = rem >> 5, s = rem & 31;            // row 0..17, quad 0..31
    int ih = oh0 * 2 - 1 + r;
    act[u] = (sg < NSLOT) && ((unsigned)ih < 128u);
    xdw[u] = p * XPLANE + r * XRLEN + 4 * s + 3;
    int ch = 2 * p;                             // chunk-local even channel
    gpA[u] = x + (((size_t)(b * 64 + ch) << 14) + (size_t)ih * 128 + 4 * s);
  }

  float4 xva[3], xvb[3];
  auto XLOAD = [&](int c) {
    #pragma unroll
    for (int u = 0; u < 3; ++u)
      if (act[u]) {
        const float* p = gpA[u] + (size_t)c * 131072;  // 8 channels * 16384 floats
        xva[u] = *(const float4*)p;                    // ch even
        xvb[u] = *(const float4*)(p + 16384);          // ch odd
      }
  };
  auto XWRITE = [&](int nb) {
    u32* X = (u32*)(lds + 65536 + nb * XBYTES);
    #pragma unroll
    for (int u = 0; u < 3; ++u)
      if (act[u]) {
        u32 w0 = pack2(xva[u].x, xvb[u].x);
        u32 w1 = pack2(xva[u].y, xvb[u].y);
        u32 w2 = pack2(xva[u].z, xvb[u].z);
        u32 w3 = pack2(xva[u].w, xvb[u].w);
        X[xdw[u]] = w0;                                   // ci 4s+3 (b32)
        uint2 mid; mid.x = w1; mid.y = w2;
        *(uint2*)(X + xdw[u] + 1) = mid;                  // ci 4s+4..5 (aligned b64)
        X[xdw[u] + 3] = w3;                               // ci 4s+6 (b32)
      }
  };

  // ---- A staging: identity copy via global_load_lds, 2 KiB per wave ----
  auto ASTAGE = [&](int c, int nb) {
    const char* src = wsW + c * 32768 + w * 2048 + l * 16;
    char* dst = lds + nb * 32768 + w * 2048;     // wave-uniform base; HW adds lane*16
    __builtin_amdgcn_global_load_lds(
        (const __attribute__((address_space(1))) u32*)src,
        (__attribute__((address_space(3))) u32*)dst, 16, 0, 0);
    __builtin_amdgcn_global_load_lds(
        (const __attribute__((address_space(1))) u32*)(src + 1024),
        (__attribute__((address_space(3))) u32*)(dst + 1024), 16, 0, 0);
  };

  // ---- one-time zero fill of both X buffers (edges + OOB rows stay zero) ----
  {
    u32* X = (u32*)(lds + 65536);
    for (int i = tid; i < 2 * XBYTES / 4; i += 1024) X[i] = 0;
  }

  f32x4 acc[4][4];
  #pragma unroll
  for (int mf = 0; mf < 4; ++mf)
    #pragma unroll
    for (int nf = 0; nf < 4; ++nf) acc[mf][nf] = {0.f, 0.f, 0.f, 0.f};

  // B-fragment u32 offsets (within plane 0); nfb = 4*wn + nf in 0..31
  int bo[4];
  #pragma unroll
  for (int nf = 0; nf < 4; ++nf) {
    int nfb = 4 * wn + nf;
    int owt = ((nfb & 3) << 4) + lcol;
    bo[nf] = (2 * (nfb >> 2) + t4) * XRLEN + 2 * owt + 2;
  }

  // A-fragment LDS offsets: row o = wm*64+mf*16+lcol (o&15 == lcol), 256 B rows,
  // swizzled: byte = o*256 + ((4*kk + t4) ^ (o&15))*16
  int ao[4][4];
  #pragma unroll
  for (int mf = 0; mf < 4; ++mf)
    #pragma unroll
    for (int kk = 0; kk < 4; ++kk)
      ao[mf][kk] = (wm * 64 + mf * 16 + lcol) * 256 +
                   (((4 * kk + t4) ^ lcol) << 4);

  auto COMPUTE = [&](int cb) {
    const char* Ab = lds + cb * 32768;
    const u32* Xb = (const u32*)(lds + 65536 + cb * XBYTES);
    __builtin_amdgcn_s_setprio(1);
    #pragma unroll
    for (int kk = 0; kk < 4; ++kk) {
      short8 af[4];
      #pragma unroll
      for (int mf = 0; mf < 4; ++mf)
        af[mf] = *(const short8*)(Ab + ao[mf][kk]);
      #pragma unroll
      for (int nf = 0; nf < 4; ++nf) {
        const u32* q = Xb + bo[nf] + kk * XPLANE;
        union { uint2 u2[2]; short8 s8; } bu;
        bu.u2[0] = *(const uint2*)(q);        // ci0, ci0+1 (aligned b64)
        bu.u2[1] = *(const uint2*)(q + 2);    // ci0+2, ci0+3 (aligned b64)
        short8 bf = bu.s8;
        #pragma unroll
        for (int mf = 0; mf < 4; ++mf)
          acc[mf][nf] = __builtin_amdgcn_mfma_f32_16x16x32_bf16(af[mf], bf, acc[mf][nf], 0, 0, 0);
      }
    }
    __builtin_amdgcn_s_setprio(0);
  };

  // ---- main loop: A+X double-buffered, 8 chunks (half the barrier drains) ----
  ASTAGE(0, 0); XLOAD(0);
  __syncthreads();                 // zero-fill visible before first X writes
  XWRITE(0);
  __syncthreads();                 // vmcnt drained: A0 ready too
  for (int c = 0; c < 8; ++c) {
    int cur = c & 1;
    if (c < 7) { ASTAGE(c + 1, cur ^ 1); XLOAD(c + 1); }
    COMPUTE(cur);
    if (c < 7) XWRITE(cur ^ 1);
    __syncthreads();
  }

  // ---- epilogue: conv output (C/D layout: col=lane&15, row=(lane>>4)*4+reg) ----
  size_t obase = ((size_t)b * 128) * 4096;
  if (outb) {
    #pragma unroll
    for (int mf = 0; mf < 4; ++mf)
      #pragma unroll
      for (int nf = 0; nf < 4; ++nf) {
        int nfb = 4 * wn + nf;
        int oh = oh0 + (nfb >> 2), ow = ((nfb & 3) << 4) + lcol;
        #pragma unroll
        for (int r = 0; r < 4; ++r) {
          int o = wm * 64 + mf * 16 + t4 * 4 + r;
          outb[obase + (size_t)o * 4096 + oh * 64 + ow] = f2bf(acc[mf][nf][r]);
        }
      }
  } else {
    #pragma unroll
    for (int mf = 0; mf < 4; ++mf)
      #pragma unroll
      for (int nf = 0; nf < 4; ++nf) {
        int nfb = 4 * wn + nf;
        int oh = oh0 + (nfb >> 2), ow = ((nfb & 3) << 4) + lcol;
        #pragma unroll
        for (int r = 0; r < 4; ++r) {
          int o = wm * 64 + mf * 16 + t4 * 4 + r;
          out[obase + (size_t)o * 4096 + oh * 64 + ow] = acc[mf][nf][r];
        }
      }
  }

  // ---- deterministic per-block (sum, sumsq) partials (fp32 registers) ----
  float* ps = (float*)lds;    // A0 region dead after last barrier; [128 o][8 wn][2]
  #pragma unroll
  for (int mf = 0; mf < 4; ++mf)
    #pragma unroll
    for (int r = 0; r < 4; ++r) {
      float s1 = 0.f, s2 = 0.f;
      #pragma unroll
      for (int nf = 0; nf < 4; ++nf) { float v = acc[mf][nf][r]; s1 += v; s2 += v * v; }
      #pragma unroll
      for (int d = 1; d < 16; d <<= 1) { s1 += __shfl_xor(s1, d); s2 += __shfl_xor(s2, d); }
      if (lcol == 0) {
        int o = wm * 64 + mf * 16 + t4 * 4 + r;
        ps[o * 16 + wn * 2 + 0] = s1;
        ps[o * 16 + wn * 2 + 1] = s2;
      }
    }
  __syncthreads();
  if (tid < 128) {
    float s1 = 0.f, s2 = 0.f;
    #pragma unroll
    for (int q = 0; q < 8; ++q) {
      s1 += ps[tid * 16 + q * 2 + 0];
      s2 += ps[tid * 16 + q * 2 + 1];
    }
    part[(size_t)tid * 256 + b * 8 + ohb] = make_float2(s1, s2);
  }
}

// ---------------- Kernel 3 (fast): fused stats + normalize + leaky ReLU ----------------
// Each block serves exactly one channel: o = (blockIdx>>1) & 127.
__global__ __launch_bounds__(256) void norm_stats_bf16_kernel(
    const u32* __restrict__ cb, const float2* __restrict__ part,
    const float* __restrict__ gamma, const float* __restrict__ beta,
    float* __restrict__ out) {
  const int tid = threadIdx.x;
  const int l = tid & 63, w = tid >> 6;
  const int o = (blockIdx.x >> 1) & (COUT - 1);

  // in-block stats: reduce part[o][0..255]
  float2 pv = part[(size_t)o * 256 + tid];
  float s1 = pv.x, s2 = pv.y;
  #pragma unroll
  for (int d = 1; d < 64; d <<= 1) { s1 += __shfl_xor(s1, d); s2 += __shfl_xor(s2, d); }
  __shared__ float psum[8];
  if (l == 0) { psum[w * 2] = s1; psum[w * 2 + 1] = s2; }
  __syncthreads();
  float t1 = psum[0] + psum[2] + psum[4] + psum[6];
  float t2 = psum[1] + psum[3] + psum[5] + psum[7];
  const float N = (float)BATCH * HOUT * WOUT;   // 131072
  float mean = t1 / N;
  float var  = t2 / N - mean * mean;
  float inv  = rsqrtf(var + 1e-5f);
  float a  = gamma[o] * inv;
  float bb = beta[o] - mean * a;

  size_t g = (size_t)blockIdx.x * 256 + tid;    // group of 8 elements
  uint4 pk = ((const uint4*)cb)[g];             // 8 bf16
  float e[8];
  e[0] = __uint_as_float(pk.x << 16); e[1] = __uint_as_float(pk.x & 0xffff0000u);
  e[2] = __uint_as_float(pk.y << 16); e[3] = __uint_as_float(pk.y & 0xffff0000u);
  e[4] = __uint_as_float(pk.z << 16); e[5] = __uint_as_float(pk.z & 0xffff0000u);
  e[6] = __uint_as_float(pk.w << 16); e[7] = __uint_as_float(pk.w & 0xffff0000u);
  #pragma unroll
  for (int i = 0; i < 8; ++i) {
    float v = fmaf(e[i], a, bb);
    e[i] = v >= 0.f ? v : 0.1f * v;
  }
  float4* op = (float4*)(out + g * 8);
  op[0] = make_float4(e[0], e[1], e[2], e[3]);
  op[1] = make_float4(e[4], e[5], e[6], e[7]);
}

// ---------------- Fallback: stats + in-place fp32 normalize ----------------
__global__ __launch_bounds__(256) void stats_kernel(
    const float2* __restrict__ part, const float* __restrict__ gamma,
    const float* __restrict__ beta, float2* __restrict__ ab) {
  int o = blockIdx.x;
  int tid = threadIdx.x;
  float2 p = part[(size_t)o * 256 + tid];
  float s1 = p.x, s2 = p.y;
  __shared__ float r1[256], r2[256];
  r1[tid] = s1; r2[tid] = s2;
  __syncthreads();
  for (int off = 128; off > 0; off >>= 1) {
    if (tid < off) { r1[tid] += r1[tid + off]; r2[tid] += r2[tid + off]; }
    __syncthreads();
  }
  if (tid == 0) {
    const float N = (float)BATCH * HOUT * WOUT;
    float mean = r1[0] / N;
    float var  = r2[0] / N - mean * mean;
    float inv  = rsqrtf(var + 1e-5f);
    float a = gamma[o] * inv;
    float bb = beta[o] - mean * a;
    ab[o] = make_float2(a, bb);
  }
}

__global__ __launch_bounds__(256) void norm_kernel(
    float* __restrict__ out, const float2* __restrict__ ab) {
  size_t idx = (size_t)blockIdx.x * 256 + threadIdx.x;
  int o = (int)((idx >> 10) & (COUT - 1));
  float2 s = ab[o];
  float4 v = reinterpret_cast<float4*>(out)[idx];
  v.x = fmaf(v.x, s.x, s.y);
  v.y = fmaf(v.y, s.x, s.y);
  v.z = fmaf(v.z, s.x, s.y);
  v.w = fmaf(v.w, s.x, s.y);
  v.x = v.x >= 0.f ? v.x : 0.1f * v.x;
  v.y = v.y >= 0.f ? v.y : 0.1f * v.y;
  v.z = v.z >= 0.f ? v.z : 0.1f * v.z;
  v.w = v.w >= 0.f ? v.w : 0.1f * v.w;
  reinterpret_cast<float4*>(out)[idx] = v;
}

extern "C" void kernel_launch(void* const* d_in, const int* in_sizes, int n_in,
                              void* d_out, int out_size, void* d_ws, size_t ws_size,
                              hipStream_t stream) {
  const float* x     = (const float*)d_in[0];
  const float* freq  = (const float*)d_in[1];
  const float* theta = (const float*)d_in[2];
  const float* psi   = (const float*)d_in[3];
  const float* sigma = (const float*)d_in[4];
  const float* gamma = (const float*)d_in[5];
  const float* beta  = (const float*)d_in[6];
  float* out = (float*)d_out;

  __hip_bfloat16* wsw = (__hip_bfloat16*)d_ws;
  float2* part = (float2*)((char*)d_ws + 262144);
  float2* ab   = (float2*)((char*)d_ws + 786432);

  const size_t WSO_OFF = 1048576;
  const size_t WSO_BYTES = (size_t)BATCH * COUT * HOUT * WOUT * 2;  // 32 MiB
  bool fast = ws_size >= WSO_OFF + WSO_BYTES;
  u16* wsO = fast ? (u16*)((char*)d_ws + WSO_OFF) : nullptr;

  gabor_kernel<<<32, 256, 0, stream>>>(freq, theta, psi, sigma, wsw);
  conv_mfma<<<dim3(8, BATCH), 1024, 0, stream>>>(x, (const char*)d_ws, out, wsO, part);
  if (fast) {
    norm_stats_bf16_kernel<<<2097152 / 256, 256, 0, stream>>>(
        (const u32*)wsO, part, gamma, beta, out);
  } else {
    stats_kernel<<<COUT, 256, 0, stream>>>(part, gamma, beta, ab);
    norm_kernel<<<4194304 / 256, 256, 0, stream>>>(out, ab);
  }
}

// Round 19
// 70.398 us; speedup vs baseline: 1.0682x; 1.0682x over previous
//
#include <hip/hip_runtime.h>
#include <hip/hip_bf16.h>

#define BATCH 32
#define CIN   64
#define COUT  128
#define HIN   128
#define WIN   128
#define HOUT  64
#define WOUT  64

typedef unsigned int u32;
typedef unsigned short u16;
typedef __attribute__((ext_vector_type(8))) short short8;
typedef __attribute__((ext_vector_type(4))) float f32x4;

// ---------------- ws layout ----------------
// wsW  : byte       0 ..  262144 : bf16 weights, SWIZZLED image, 16 chunks * 16384 B
//        chunk=i>>2, kk=(i&3)>>1, parity=i&1:
//        byte = o*128 + ((4*kk+kh)^(o&7))*16 + (2*kw+parity)*2
// part : byte  262144 ..  786432 : [128][512] float2 partial sums
// ab   : byte  786432 ..  787456 : [128] float2 (fallback path only)
// wsO  : byte 1048576 .. 34603008: bf16 conv intermediate (fast path only)

__device__ inline u16 f2bf(float v) {
  __hip_bfloat16 h = __float2bfloat16(v);
  return *reinterpret_cast<u16*>(&h);
}
__device__ inline u32 pack2(float a, float b) {
  return (u32)f2bf(a) | ((u32)f2bf(b) << 16);
}

// ---------------- Kernel 1: Gabor filters -> swizzled bf16 image (R14-verified) ----------------
__global__ __launch_bounds__(256) void gabor_kernel(
    const float* __restrict__ freq, const float* __restrict__ theta,
    const float* __restrict__ psi,  const float* __restrict__ sigma,
    __hip_bfloat16* __restrict__ wsw) {
  int idx = blockIdx.x * 256 + threadIdx.x;     // 8192 = 128*64
  int o = idx >> 6, i = idx & 63;
  float f = freq[idx], t = theta[idx], p = psi[idx], s = sigma[idx];
  float ct = cosf(t), st = sinf(t);
  float se = s + 0.001f;
  float gsc = -0.5f / (se * se);
  float nrm = 1.0f / (2.0f * 3.14f * s * s);    // PI = 3.14 in the reference
  const float lin[4] = {-1.f, 0.f, 1.f, 2.f};
  int chunk = i >> 2, i4 = i & 3;
  #pragma unroll
  for (int ky = 0; ky < 4; ++ky) {
    #pragma unroll
    for (int kx = 0; kx < 4; ++kx) {
      float xx = lin[kx], yy = lin[ky];
      float rx =  xx * ct + yy * st;
      float ry = -xx * st + yy * ct;
      float g = __expf(gsc * (rx * rx + ry * ry)) * cosf(f * rx + p) * nrm;
      int sub = 4 * (i4 >> 1) + ky;
      int j = 2 * kx + (i4 & 1);
      int slot = sub ^ (o & 7);
      wsw[(chunk * 16384 + o * 128 + slot * 16 + j * 2) >> 1] = __float2bfloat16(g);
    }
  }
}

// ---------------- Kernel 2: implicit-GEMM conv via MFMA ----------------
// 2 blocks/CU geometry (the m97 implicit-overlap mechanism): grid 512 = 16 ohb x 32 b,
// 512 thr (8 waves, 2M x 4N). Tile M=128 x N=256 (4 oh x 64 ow). K: 16 chunks of 64.
// A via global_load_lds (R14 swizzled image); X channel-pair u32 [2 planes][10 rows][136].
constexpr int XRLEN  = 136;   // u32 per row (ci = iw+3, 0..135)
constexpr int XROWS  = 10;    // ih rows (4 oh -> 10 with halo)
constexpr int XPLANE = 1360;  // u32 per plane (10*136)
constexpr int XBYTES = 10880; // 2 planes * 1360 u32 * 4 B
constexpr int NSLOT  = 640;   // 2 planes * 10 rows * 32 quads
// LDS: A0 @0, A1 @16384, X0 @32768, X1 @43648 ; total 54528 -> 2 blocks/CU

__global__ __launch_bounds__(512, 4) void conv_mfma(
    const float* __restrict__ x, const char* __restrict__ wsW,
    float* __restrict__ out, u16* __restrict__ outb,
    float2* __restrict__ part) {
  __shared__ __align__(16) char lds[54528];

  const int tid = threadIdx.x;
  const int l = tid & 63, w = tid >> 6;       // 8 waves
  const int wm = w & 1, wn = w >> 1;          // wm: M-half, wn: N-quarter (0..3)
  const int t4 = l >> 4, lcol = l & 15;
  const int ohb = blockIdx.x, b = blockIdx.y;
  const int oh0 = ohb * 4;

  // ---- X staging precompute: 2 slots/thread, sg = tid + u*512 (covers 640) ----
  bool act[2]; int xdw[2]; const float* gpA[2];
  #pragma unroll
  for (int u = 0; u < 2; ++u) {
    int sg = tid + u * 512;
    int p = sg / 320, rem = sg - p * 320;      // plane = channel pair (0..1)
    int r = rem >> 5, s = rem & 31;            // row 0..9, quad 0..31
    int ih = oh0 * 2 - 1 + r;
    act[u] = (sg < NSLOT) && ((unsigned)ih < 128u);
    xdw[u] = p * XPLANE + r * XRLEN + 4 * s + 3;
    int ch = 2 * p;                             // chunk-local even channel
    gpA[u] = x + (((size_t)(b * 64 + ch) << 14) + (size_t)ih * 128 + 4 * s);
  }

  float4 xva[2], xvb[2];
  auto XLOAD = [&](int c) {
    #pragma unroll
    for (int u = 0; u < 2; ++u)
      if (act[u]) {
        const float* p = gpA[u] + (size_t)c * 65536;   // 4 channels * 16384 floats
        xva[u] = *(const float4*)p;                    // ch even
        xvb[u] = *(const float4*)(p + 16384);          // ch odd
      }
  };
  auto XWRITE = [&](int nb) {
    u32* X = (u32*)(lds + 32768 + nb * XBYTES);
    #pragma unroll
    for (int u = 0; u < 2; ++u)
      if (act[u]) {
        u32 w0 = pack2(xva[u].x, xvb[u].x);
        u32 w1 = pack2(xva[u].y, xvb[u].y);
        u32 w2 = pack2(xva[u].z, xvb[u].z);
        u32 w3 = pack2(xva[u].w, xvb[u].w);
        X[xdw[u]] = w0;                                   // ci 4s+3 (b32)
        uint2 mid; mid.x = w1; mid.y = w2;
        *(uint2*)(X + xdw[u] + 1) = mid;                  // ci 4s+4..5 (aligned b64)
        X[xdw[u] + 3] = w3;                               // ci 4s+6 (b32)
      }
  };

  // ---- A staging: identity copy via global_load_lds, 2 KiB per wave ----
  auto ASTAGE = [&](int c, int nb) {
    const char* src = wsW + c * 16384 + w * 2048 + l * 16;
    char* dst = lds + nb * 16384 + w * 2048;     // wave-uniform base; HW adds lane*16
    __builtin_amdgcn_global_load_lds(
        (const __attribute__((address_space(1))) u32*)src,
        (__attribute__((address_space(3))) u32*)dst, 16, 0, 0);
    __builtin_amdgcn_global_load_lds(
        (const __attribute__((address_space(1))) u32*)(src + 1024),
        (__attribute__((address_space(3))) u32*)(dst + 1024), 16, 0, 0);
  };

  // ---- one-time zero fill of both X buffers (edges + OOB rows stay zero) ----
  {
    u32* X = (u32*)(lds + 32768);
    for (int i = tid; i < 2 * XBYTES / 4; i += 512) X[i] = 0;
  }

  f32x4 acc[4][4];
  #pragma unroll
  for (int mf = 0; mf < 4; ++mf)
    #pragma unroll
    for (int nf = 0; nf < 4; ++nf) acc[mf][nf] = {0.f, 0.f, 0.f, 0.f};

  // B-fragment u32 offsets (within plane 0); nfb = 4*wn + nf in 0..15
  int bo[4];
  #pragma unroll
  for (int nf = 0; nf < 4; ++nf) {
    int nfb = 4 * wn + nf;
    int owt = ((nfb & 3) << 4) + lcol;
    bo[nf] = (2 * (nfb >> 2) + t4) * XRLEN + 2 * owt + 2;
  }

  // A-fragment LDS offsets (swizzled, 128 B rows)
  int ao[4][2];
  #pragma unroll
  for (int mf = 0; mf < 4; ++mf)
    #pragma unroll
    for (int kk = 0; kk < 2; ++kk)
      ao[mf][kk] = (wm * 64 + mf * 16 + lcol) * 128 +
                   (((4 * kk + t4) ^ (lcol & 7)) << 4);

  auto COMPUTE = [&](int cb) {
    const char* Ab = lds + cb * 16384;
    const u32* Xb = (const u32*)(lds + 32768 + cb * XBYTES);
    __builtin_amdgcn_s_setprio(1);
    #pragma unroll
    for (int kk = 0; kk < 2; ++kk) {
      short8 af[4];
      #pragma unroll
      for (int mf = 0; mf < 4; ++mf)
        af[mf] = *(const short8*)(Ab + ao[mf][kk]);
      #pragma unroll
      for (int nf = 0; nf < 4; ++nf) {
        const u32* q = Xb + bo[nf] + kk * XPLANE;
        union { uint2 u2[2]; short8 s8; } bu;
        bu.u2[0] = *(const uint2*)(q);        // ci0, ci0+1 (aligned b64)
        bu.u2[1] = *(const uint2*)(q + 2);    // ci0+2, ci0+3 (aligned b64)
        short8 bf = bu.s8;
        #pragma unroll
        for (int mf = 0; mf < 4; ++mf)
          acc[mf][nf] = __builtin_amdgcn_mfma_f32_16x16x32_bf16(af[mf], bf, acc[mf][nf], 0, 0, 0);
      }
    }
    __builtin_amdgcn_s_setprio(0);
  };

  // ---- main loop: A+X double-buffered, loads issued early ----
  ASTAGE(0, 0); XLOAD(0);
  __syncthreads();                 // zero-fill visible before first X writes
  XWRITE(0);
  __syncthreads();                 // vmcnt drained: A0 ready too
  for (int c = 0; c < 16; ++c) {
    int cur = c & 1;
    if (c < 15) { ASTAGE(c + 1, cur ^ 1); XLOAD(c + 1); }
    COMPUTE(cur);
    if (c < 15) XWRITE(cur ^ 1);
    __syncthreads();
  }

  // ---- epilogue: conv output (C/D layout: col=lane&15, row=(lane>>4)*4+reg) ----
  size_t obase = ((size_t)b * 128) * 4096;
  if (outb) {
    #pragma unroll
    for (int mf = 0; mf < 4; ++mf)
      #pragma unroll
      for (int nf = 0; nf < 4; ++nf) {
        int nfb = 4 * wn + nf;
        int oh = oh0 + (nfb >> 2), ow = ((nfb & 3) << 4) + lcol;
        #pragma unroll
        for (int r = 0; r < 4; ++r) {
          int o = wm * 64 + mf * 16 + t4 * 4 + r;
          outb[obase + (size_t)o * 4096 + oh * 64 + ow] = f2bf(acc[mf][nf][r]);
        }
      }
  } else {
    #pragma unroll
    for (int mf = 0; mf < 4; ++mf)
      #pragma unroll
      for (int nf = 0; nf < 4; ++nf) {
        int nfb = 4 * wn + nf;
        int oh = oh0 + (nfb >> 2), ow = ((nfb & 3) << 4) + lcol;
        #pragma unroll
        for (int r = 0; r < 4; ++r) {
          int o = wm * 64 + mf * 16 + t4 * 4 + r;
          out[obase + (size_t)o * 4096 + oh * 64 + ow] = acc[mf][nf][r];
        }
      }
  }

  // ---- deterministic per-block (sum, sumsq) partials (fp32 registers) ----
  float* ps = (float*)lds;    // A0 region dead after last barrier; [128 o][4 wn][2]
  #pragma unroll
  for (int mf = 0; mf < 4; ++mf)
    #pragma unroll
    for (int r = 0; r < 4; ++r) {
      float s1 = 0.f, s2 = 0.f;
      #pragma unroll
      for (int nf = 0; nf < 4; ++nf) { float v = acc[mf][nf][r]; s1 += v; s2 += v * v; }
      #pragma unroll
      for (int d = 1; d < 16; d <<= 1) { s1 += __shfl_xor(s1, d); s2 += __shfl_xor(s2, d); }
      if (lcol == 0) {
        int o = wm * 64 + mf * 16 + t4 * 4 + r;
        ps[o * 8 + wn * 2 + 0] = s1;
        ps[o * 8 + wn * 2 + 1] = s2;
      }
    }
  __syncthreads();
  if (tid < 128) {
    float s1 = 0.f, s2 = 0.f;
    #pragma unroll
    for (int q = 0; q < 4; ++q) {
      s1 += ps[tid * 8 + q * 2 + 0];
      s2 += ps[tid * 8 + q * 2 + 1];
    }
    part[(size_t)tid * 512 + b * 16 + ohb] = make_float2(s1, s2);
  }
}

// ---------------- Kernel 3 (fast): fused stats + normalize + leaky ReLU ----------------
// Each block serves exactly one channel: o = (blockIdx>>1) & 127.
__global__ __launch_bounds__(256) void norm_stats_bf16_kernel(
    const u32* __restrict__ cb, const float2* __restrict__ part,
    const float* __restrict__ gamma, const float* __restrict__ beta,
    float* __restrict__ out) {
  const int tid = threadIdx.x;
  const int l = tid & 63, w = tid >> 6;
  const int o = (blockIdx.x >> 1) & (COUT - 1);

  // in-block stats: reduce part[o][0..511] (2 entries/thread)
  float2 p0 = part[(size_t)o * 512 + tid];
  float2 p1 = part[(size_t)o * 512 + tid + 256];
  float s1 = p0.x + p1.x, s2 = p0.y + p1.y;
  #pragma unroll
  for (int d = 1; d < 64; d <<= 1) { s1 += __shfl_xor(s1, d); s2 += __shfl_xor(s2, d); }
  __shared__ float psum[8];
  if (l == 0) { psum[w * 2] = s1; psum[w * 2 + 1] = s2; }
  __syncthreads();
  float t1 = psum[0] + psum[2] + psum[4] + psum[6];
  float t2 = psum[1] + psum[3] + psum[5] + psum[7];
  const float N = (float)BATCH * HOUT * WOUT;   // 131072
  float mean = t1 / N;
  float var  = t2 / N - mean * mean;
  float inv  = rsqrtf(var + 1e-5f);
  float a  = gamma[o] * inv;
  float bb = beta[o] - mean * a;

  size_t g = (size_t)blockIdx.x * 256 + tid;    // group of 8 elements
  uint4 pk = ((const uint4*)cb)[g];             // 8 bf16
  float e[8];
  e[0] = __uint_as_float(pk.x << 16); e[1] = __uint_as_float(pk.x & 0xffff0000u);
  e[2] = __uint_as_float(pk.y << 16); e[3] = __uint_as_float(pk.y & 0xffff0000u);
  e[4] = __uint_as_float(pk.z << 16); e[5] = __uint_as_float(pk.z & 0xffff0000u);
  e[6] = __uint_as_float(pk.w << 16); e[7] = __uint_as_float(pk.w & 0xffff0000u);
  #pragma unroll
  for (int i = 0; i < 8; ++i) {
    float v = fmaf(e[i], a, bb);
    e[i] = v >= 0.f ? v : 0.1f * v;
  }
  float4* op = (float4*)(out + g * 8);
  op[0] = make_float4(e[0], e[1], e[2], e[3]);
  op[1] = make_float4(e[4], e[5], e[6], e[7]);
}

// ---------------- Fallback: stats + in-place fp32 normalize ----------------
__global__ __launch_bounds__(256) void stats_kernel(
    const float2* __restrict__ part, const float* __restrict__ gamma,
    const float* __restrict__ beta, float2* __restrict__ ab) {
  int o = blockIdx.x;
  int tid = threadIdx.x;
  float s1 = 0.f, s2 = 0.f;
  #pragma unroll
  for (int t = 0; t < 2; ++t) {
    float2 p = part[(size_t)o * 512 + tid + t * 256];
    s1 += p.x; s2 += p.y;
  }
  __shared__ float r1[256], r2[256];
  r1[tid] = s1; r2[tid] = s2;
  __syncthreads();
  for (int off = 128; off > 0; off >>= 1) {
    if (tid < off) { r1[tid] += r1[tid + off]; r2[tid] += r2[tid + off]; }
    __syncthreads();
  }
  if (tid == 0) {
    const float N = (float)BATCH * HOUT * WOUT;
    float mean = r1[0] / N;
    float var  = r2[0] / N - mean * mean;
    float inv  = rsqrtf(var + 1e-5f);
    float a = gamma[o] * inv;
    float bb = beta[o] - mean * a;
    ab[o] = make_float2(a, bb);
  }
}

__global__ __launch_bounds__(256) void norm_kernel(
    float* __restrict__ out, const float2* __restrict__ ab) {
  size_t idx = (size_t)blockIdx.x * 256 + threadIdx.x;
  int o = (int)((idx >> 10) & (COUT - 1));
  float2 s = ab[o];
  float4 v = reinterpret_cast<float4*>(out)[idx];
  v.x = fmaf(v.x, s.x, s.y);
  v.y = fmaf(v.y, s.x, s.y);
  v.z = fmaf(v.z, s.x, s.y);
  v.w = fmaf(v.w, s.x, s.y);
  v.x = v.x >= 0.f ? v.x : 0.1f * v.x;
  v.y = v.y >= 0.f ? v.y : 0.1f * v.y;
  v.z = v.z >= 0.f ? v.z : 0.1f * v.z;
  v.w = v.w >= 0.f ? v.w : 0.1f * v.w;
  reinterpret_cast<float4*>(out)[idx] = v;
}

extern "C" void kernel_launch(void* const* d_in, const int* in_sizes, int n_in,
                              void* d_out, int out_size, void* d_ws, size_t ws_size,
                              hipStream_t stream) {
  const float* x     = (const float*)d_in[0];
  const float* freq  = (const float*)d_in[1];
  const float* theta = (const float*)d_in[2];
  const float* psi   = (const float*)d_in[3];
  const float* sigma = (const float*)d_in[4];
  const float* gamma = (const float*)d_in[5];
  const float* beta  = (const float*)d_in[6];
  float* out = (float*)d_out;

  __hip_bfloat16* wsw = (__hip_bfloat16*)d_ws;
  float2* part = (float2*)((char*)d_ws + 262144);
  float2* ab   = (float2*)((char*)d_ws + 786432);

  const size_t WSO_OFF = 1048576;
  const size_t WSO_BYTES = (size_t)BATCH * COUT * HOUT * WOUT * 2;  // 32 MiB
  bool fast = ws_size >= WSO_OFF + WSO_BYTES;
  u16* wsO = fast ? (u16*)((char*)d_ws + WSO_OFF) : nullptr;

  gabor_kernel<<<32, 256, 0, stream>>>(freq, theta, psi, sigma, wsw);
  conv_mfma<<<dim3(16, BATCH), 512, 0, stream>>>(x, (const char*)d_ws, out, wsO, part);
  if (fast) {
    norm_stats_bf16_kernel<<<2097152 / 256, 256, 0, stream>>>(
        (const u32*)wsO, part, gamma, beta, out);
  } else {
    stats_kernel<<<COUT, 256, 0, stream>>>(part, gamma, beta, ab);
    norm_kernel<<<4194304 / 256, 256, 0, stream>>>(out, ab);
  }
}